// Round 8
// baseline (452.957 us; speedup 1.0000x reference)
//
#include <hip/hip_runtime.h>
#include <cstdint>

typedef _Float16 f16;
typedef f16 f16x8 __attribute__((ext_vector_type(8)));
typedef f16 f16x4 __attribute__((ext_vector_type(4)));
typedef f16 f16x2 __attribute__((ext_vector_type(2)));
typedef float f32x4 __attribute__((ext_vector_type(4)));
typedef uint32_t u32x4 __attribute__((ext_vector_type(4)));

#define D_MODEL 1280
#define SEQ 2048
#define BATCH 4
#define HEADS 8
#define HDIM 160
#define MTOT (BATCH*SEQ)          // 8192
#define NQKV (3*D_MODEL)          // 3840

__device__ __forceinline__ void gload_lds16(const f16* g, f16* l) {
  __builtin_amdgcn_global_load_lds(
      (const __attribute__((address_space(1))) unsigned int*)g,
      (__attribute__((address_space(3))) unsigned int*)l,
      16, 0, 0);
}

#define BARX() { asm volatile("" ::: "memory"); __builtin_amdgcn_s_barrier(); asm volatile("" ::: "memory"); }
#define VMW(N) { asm volatile("s_waitcnt vmcnt(" #N ")" ::: "memory"); }

// ---------------- prep kernels ----------------

__global__ void convert_f32_to_f16(const float* __restrict__ in, f16* __restrict__ out, int n4) {
  int i = blockIdx.x * 256 + threadIdx.x;
  if (i < n4) {
    float4 v = ((const float4*)in)[i];
    f16x4 o = { (f16)v.x, (f16)v.y, (f16)v.z, (f16)v.w };
    ((f16x4*)out)[i] = o;
  }
}

// W_eff[o][i] = W[o][i] + sum_r up[o][r]*down[r][i]   (all 1280x1280, rank 4)
__global__ void build_weff(const float* __restrict__ W, const float* __restrict__ up,
                           const float* __restrict__ down, f16* __restrict__ out) {
  int idx = blockIdx.x * 256 + threadIdx.x;          // D*D/4 threads
  int o  = idx / (D_MODEL / 4);
  int i0 = (idx % (D_MODEL / 4)) * 4;
  float4 w = *(const float4*)&W[(size_t)o * D_MODEL + i0];
  float u0 = up[o*4+0], u1 = up[o*4+1], u2 = up[o*4+2], u3 = up[o*4+3];
  float vals[4] = { w.x, w.y, w.z, w.w };
  f16x4 r;
#pragma unroll
  for (int j = 0; j < 4; ++j) {
    int i = i0 + j;
    float acc = vals[j] + u0*down[i] + u1*down[D_MODEL + i]
                        + u2*down[2*D_MODEL + i] + u3*down[3*D_MODEL + i];
    r[j] = (f16)acc;
  }
  *(f16x4*)&out[(size_t)o * D_MODEL + i0] = r;
}

// V slice of qkv [8192][3840] (cols 2560..3839) -> Vt [32 bh][160 d][2048 s]
// s-index sigma-permuted within each 32-block: sigma swaps 4-blocks [4-7]<->[8-11]
// and [20-23]<->[24-27] (involution), matching the in-register P layout.
__global__ void transpose_v(const f16* __restrict__ qkv, f16* __restrict__ Vt) {
  __shared__ f16 t[32][33];
  int s0 = blockIdx.x * 32;
  int d0 = blockIdx.y * 32;
  int bh = blockIdx.z;
  int b = bh >> 3, h = bh & 7;
  int j = threadIdx.x & 31;
  int i0 = threadIdx.x >> 5;
#pragma unroll
  for (int k = 0; k < 4; ++k) {
    int i = i0 + k * 8;
    t[i][j] = qkv[(size_t)(b*SEQ + s0 + i) * NQKV + 2*D_MODEL + h*HDIM + d0 + j];
  }
  __syncthreads();
  int sj = (((j>>2) ^ (j>>3)) & 1) ? (j ^ 12) : j;
#pragma unroll
  for (int k = 0; k < 4; ++k) {
    int i = i0 + k * 8;
    Vt[(size_t)(bh*HDIM + d0 + i) * SEQ + s0 + sj] = t[j][i];
  }
}

// ---------------- 256x256 deep-pipelined GEMM: C[M][N](f16) = A[M][K] * Bw[N][K]^T ----
__global__ __launch_bounds__(512) void gemm256(const f16* __restrict__ A,
                                               const f16* __restrict__ Bw,
                                               f16* __restrict__ C) {
  const int K = D_MODEL, ldc = NQKV, NT = D_MODEL/64;   // 20 K-tiles
  __shared__ alignas(16) f16 lds[7 * 8192];             // A: slots 0..2, B: slots 3..6
  f16* LB = lds + 3*8192;
  int tid = threadIdx.x;
  int wv = tid >> 6, l = tid & 63;
  int wm = wv >> 2, wn = wv & 3;
  int lr = l & 15, lg = l >> 4;
  int bm = blockIdx.y, bn = blockIdx.x;

  int row0 = tid >> 3;
  int csw  = ((tid & 7) ^ (row0 & 7)) * 8;
  const f16* Asrc[2]; const f16* Bsrc[2];
#pragma unroll
  for (int h = 0; h < 2; ++h) {
    Asrc[h] = A  + (size_t)(bm*256 + h*128 + row0) * K + csw;
    Bsrc[h] = Bw + (size_t)(bn*256 + h*128 + row0) * K + csw;
  }
  int ldsoff = wv * 512;

  int xsl0 = ((lg)     ^ (lr & 7)) * 8;
  int xsl1 = ((4 + lg) ^ (lr & 7)) * 8;

  f32x4 acc[8][4] = {};

#define STAGE_A(h, slot, kt) { const f16* s_ = Asrc[h] + (kt)*64; f16* d_ = lds + (slot)*8192 + ldsoff; \
    gload_lds16(s_, d_); gload_lds16(s_ + (size_t)64*K, d_ + 4096); }
#define STAGE_B(h, slot, kt) { const f16* s_ = Bsrc[h] + (kt)*64; f16* d_ = LB + (slot)*8192 + ldsoff; \
    gload_lds16(s_, d_); gload_lds16(s_ + (size_t)64*K, d_ + 4096); }

  STAGE_A(0, 0, 0); STAGE_A(1, 1, 0);
  STAGE_B(0, 0, 0); STAGE_B(1, 1, 0);
  STAGE_B(0, 2, 1);
  VMW(2); BARX();

  for (int t = 0; t < NT; ++t) {
    int sA0 = (2*t) % 3, sA1 = (2*t+1) % 3, sA2 = (2*t+2) % 3;
    int sB0 = (2*t) & 3, sB1 = (2*t+1) & 3, sB3 = (2*t+3) & 3;
    int tc1 = (t+1 < NT) ? t+1 : NT-1;
    int tc2 = (t+2 < NT) ? t+2 : NT-1;

#define PHASE(ah, bh, sA, sB, STG, VMOPT) { \
    f16x8 af[4][2], bf[2][2]; \
    _Pragma("unroll") \
    for (int j = 0; j < 4; ++j) { \
      int base = (sA)*8192 + (wm*64 + j*16 + lr)*64; \
      af[j][0] = *(const f16x8*)&lds[base + xsl0]; \
      af[j][1] = *(const f16x8*)&lds[base + xsl1]; \
    } \
    _Pragma("unroll") \
    for (int i = 0; i < 2; ++i) { \
      int base = (sB)*8192 + (wn*32 + i*16 + lr)*64; \
      bf[i][0] = *(const f16x8*)&LB[base + xsl0]; \
      bf[i][1] = *(const f16x8*)&LB[base + xsl1]; \
    } \
    STG; \
    BARX(); \
    __builtin_amdgcn_s_setprio(1); \
    _Pragma("unroll") \
    for (int j = 0; j < 4; ++j) \
      _Pragma("unroll") \
      for (int i = 0; i < 2; ++i) { \
        acc[(ah)*4+j][(bh)*2+i] = __builtin_amdgcn_mfma_f32_16x16x32_f16(af[j][0], bf[i][0], acc[(ah)*4+j][(bh)*2+i], 0, 0, 0); \
        acc[(ah)*4+j][(bh)*2+i] = __builtin_amdgcn_mfma_f32_16x16x32_f16(af[j][1], bf[i][1], acc[(ah)*4+j][(bh)*2+i], 0, 0, 0); \
      } \
    __builtin_amdgcn_s_setprio(0); \
    VMOPT; \
    BARX(); }

    PHASE(0, 0, sA0, sB0, STAGE_B(1, sB3, tc1), VMW(2))
    PHASE(1, 0, sA1, sB0, STAGE_A(0, sA2, tc1), )
    PHASE(0, 1, sA0, sB1, STAGE_B(0, sB0, tc2), )
    PHASE(1, 1, sA1, sB1, STAGE_A(1, sA0, tc1), VMW(4))
#undef PHASE
  }

#pragma unroll
  for (int mf = 0; mf < 8; ++mf) {
    int r0 = bm*256 + (mf>>2)*128 + wm*64 + (mf&3)*16 + lg*4;
#pragma unroll
    for (int nf = 0; nf < 4; ++nf) {
      int c = bn*256 + (nf>>1)*128 + wn*32 + (nf&1)*16 + lr;
#pragma unroll
      for (int rg = 0; rg < 4; ++rg)
        C[(size_t)(r0 + rg) * ldc + c] = (f16)acc[mf][nf][rg];
    }
  }
#undef STAGE_A
#undef STAGE_B
}

// ---------------- GEMM: C[M][N] = A[M][K] * Bw[N][K]^T  (+bias, f32 out) ----------------

template<int OUTF16>
__global__ __launch_bounds__(256) void gemm_bt(
    const f16* __restrict__ A, int lda,
    const f16* __restrict__ Bw,                 // [N][K], ldb = K
    void* __restrict__ Cp, int ldc,
    const float* __restrict__ bias,
    int N, int K) {
  __shared__ alignas(16) f16 As[128 * 32];
  __shared__ alignas(16) f16 Bs[128 * 32];
  int tid = threadIdx.x;
  int w = tid >> 6, l = tid & 63;
  int wm = w >> 1, wn = w & 1;
  int bm = blockIdx.y, bn = blockIdx.x;
  int lr = l & 15, lg = l >> 4;

  f32x4 acc[4][4] = {};

  const int srow = w * 32 + (l >> 2);
  const int scol = (l & 3) * 8;
  const f16* Ab = A  + (size_t)(bm*128 + srow) * lda + scol;
  const f16* Bb = Bw + (size_t)(bn*128 + srow) * K   + scol;
  f16* AsW = &As[w * 1024];
  f16* BsW = &Bs[w * 1024];

  for (int k0 = 0; k0 < K; k0 += 32) {
    gload_lds16(Ab + k0,                     AsW);
    gload_lds16(Ab + k0 + (size_t)16 * lda,  AsW + 512);
    gload_lds16(Bb + k0,                     BsW);
    gload_lds16(Bb + k0 + (size_t)16 * K,    BsW + 512);
    __syncthreads();
    f16x8 af[4], bf[4];
#pragma unroll
    for (int f = 0; f < 4; ++f) {
      af[f] = *(const f16x8*)&As[(wm*64 + f*16 + lr) * 32 + lg * 8];
      bf[f] = *(const f16x8*)&Bs[(wn*64 + f*16 + lr) * 32 + lg * 8];
    }
    __builtin_amdgcn_s_setprio(1);
#pragma unroll
    for (int fr = 0; fr < 4; ++fr)
#pragma unroll
      for (int fc = 0; fc < 4; ++fc)
        acc[fr][fc] = __builtin_amdgcn_mfma_f32_16x16x32_f16(af[fr], bf[fc], acc[fr][fc], 0, 0, 0);
    __builtin_amdgcn_s_setprio(0);
    __syncthreads();
  }

#pragma unroll
  for (int fr = 0; fr < 4; ++fr) {
    int r0 = bm*128 + wm*64 + fr*16 + lg*4;
#pragma unroll
    for (int fc = 0; fc < 4; ++fc) {
      int c = bn*128 + wn*64 + fc*16 + lr;
#pragma unroll
      for (int rg = 0; rg < 4; ++rg) {
        size_t off = (size_t)(r0 + rg) * ldc + c;
        if (OUTF16) ((f16*)Cp)[off] = (f16)acc[fr][fc][rg];
        else        ((float*)Cp)[off] = acc[fr][fc][rg] + bias[c];
      }
    }
  }
}

// ---------------- flash attention v4b ----------------
// Same as v4 (R7) but the P repack uses named scalars + __builtin_bit_cast
// (register-only) instead of a union — the union allocated a stack object and
// caused ~650 MB of scratch HBM traffic.
__global__ __launch_bounds__(256, 3) void attn(const f16* __restrict__ qkv,
                                               const f16* __restrict__ Vt,
                                               f16* __restrict__ ctx) {
  __shared__ alignas(16) f16 Kl[64 * 168];    // 21504 B
  __shared__ alignas(16) f16 Vl[160 * 64];    // 20480 B
  int tid = threadIdx.x;
  int wv = tid >> 6, l = tid & 63;
  int lr = l & 15, lg = l >> 4;
  int qt = blockIdx.x, bh = blockIdx.y;
  int b = bh >> 3, h = bh & 7;
  size_t qrow[2];
#pragma unroll
  for (int qg = 0; qg < 2; ++qg)
    qrow[qg] = (size_t)(b*SEQ + qt*128 + wv*32 + qg*16 + lr);

  // Q fragments, pre-scaled by hd^-0.5 * log2(e) (exp2 domain)
  const f16 qscale = (f16)0.114055069f;
  f16x8 qf[2][5];
#pragma unroll
  for (int qg = 0; qg < 2; ++qg)
#pragma unroll
    for (int dk = 0; dk < 5; ++dk) {
      f16x8 t = *(const f16x8*)&qkv[qrow[qg] * NQKV + h*HDIM + dk*32 + lg*8];
#pragma unroll
      for (int j = 0; j < 8; ++j) t[j] = t[j] * qscale;
      qf[qg][dk] = t;
    }

  // K staging: 1344 chunks (5x256 + 64 on wave 0); slot 20 = pad (garbage ok).
  const char* Kg0 = (const char*)qkv + (size_t)(b*SEQ)*NQKV*2 + (size_t)D_MODEL*2 + (size_t)h*HDIM*2;
  char* KlB = (char*)Kl;
  uint32_t koff[6];
  f16* kld[6];
#pragma unroll
  for (int it = 0; it < 6; ++it) {
    int p = (it < 5) ? it*256 + tid : 1280 + (tid & 63);
    koff[it] = (uint32_t)(p/21) * (NQKV*2) + (uint32_t)(p%21) * 16;
    kld[it] = (f16*)(KlB + ((it < 5) ? (it*256 + wv*64)*16 : 1280*16));
  }

  // V staging: 1280 chunks; content XOR-swizzled (phys slot sp holds logical sp^(row&7)).
  const char* Vg0 = (const char*)Vt + (size_t)bh*HDIM*SEQ*2;
  char* VlB = (char*)Vl;
  uint32_t voff[5];
  f16* vld[5];
#pragma unroll
  for (int it = 0; it < 5; ++it) {
    int c = it*256 + tid;
    int row = c >> 3, sp = c & 7;
    voff[it] = (uint32_t)row * (SEQ*2) + (uint32_t)((sp ^ (row & 7)) * 16);
    vld[it] = (f16*)(VlB + (it*256 + wv*64)*16);
  }
  uint32_t vro[2];
#pragma unroll
  for (int ks = 0; ks < 2; ++ks)
    vro[ks] = (uint32_t)lr*128 + (uint32_t)((((ks*4+lg) ^ (lr & 7)) * 16));

  f32x4 oacc[10][2] = {};
  float m[2] = {-1e30f, -1e30f}, lsum[2] = {0.f, 0.f};

  for (int kt = 0; kt < 32; ++kt) {
    const char* Ksrc = Kg0 + (size_t)kt * (64*NQKV*2);
    const char* Vsrc = Vg0 + (size_t)kt * 128;
#pragma unroll
    for (int it = 0; it < 5; ++it) {
      gload_lds16((const f16*)(Ksrc + koff[it]), kld[it]);
      gload_lds16((const f16*)(Vsrc + voff[it]), vld[it]);
    }
    if (wv == 0)
      gload_lds16((const f16*)(Ksrc + koff[5]), kld[5]);
    __syncthreads();

    // S^T[kr][q], both q-groups share each K fragment
    f32x4 sc[4][2] = {};
    __builtin_amdgcn_s_setprio(1);
#pragma unroll
    for (int kb = 0; kb < 4; ++kb)
#pragma unroll
      for (int dk = 0; dk < 5; ++dk) {
        f16x8 a = *(const f16x8*)&Kl[(kb*16 + lr)*168 + dk*32 + lg*8];
        sc[kb][0] = __builtin_amdgcn_mfma_f32_16x16x32_f16(a, qf[0][dk], sc[kb][0], 0, 0, 0);
        sc[kb][1] = __builtin_amdgcn_mfma_f32_16x16x32_f16(a, qf[1][dk], sc[kb][1], 0, 0, 0);
      }
    __builtin_amdgcn_s_setprio(0);

    // online softmax (exp2 domain), lane owns q-rows qrow[0], qrow[1]
    float ps[2][16];
    float smax[2] = {-1e30f, -1e30f};
#pragma unroll
    for (int qg = 0; qg < 2; ++qg)
#pragma unroll
      for (int kb = 0; kb < 4; ++kb)
#pragma unroll
        for (int rg = 0; rg < 4; ++rg) {
          float s = sc[kb][qg][rg];
          ps[qg][kb*4 + rg] = s;
          smax[qg] = fmaxf(smax[qg], s);
        }
#pragma unroll
    for (int qg = 0; qg < 2; ++qg) {
      smax[qg] = fmaxf(smax[qg], __shfl_xor(smax[qg], 16));
      smax[qg] = fmaxf(smax[qg], __shfl_xor(smax[qg], 32));
    }
    if (!__all(fmaxf(smax[0] - m[0], smax[1] - m[1]) <= 11.54f)) {
#pragma unroll
      for (int qg = 0; qg < 2; ++qg) {
        float mn = fmaxf(m[qg], smax[qg]);
        float alpha = exp2f(m[qg] - mn);
#pragma unroll
        for (int df = 0; df < 10; ++df)
#pragma unroll
          for (int rg = 0; rg < 4; ++rg) oacc[df][qg][rg] *= alpha;
        lsum[qg] *= alpha;
        m[qg] = mn;
      }
    }
#pragma unroll
    for (int qg = 0; qg < 2; ++qg) {
      float psum = 0.f;
#pragma unroll
      for (int i = 0; i < 16; ++i) { float p = exp2f(ps[qg][i] - m[qg]); ps[qg][i] = p; psum += p; }
      psum += __shfl_xor(psum, 16);
      psum += __shfl_xor(psum, 32);
      lsum[qg] += psum;
    }

    // P -> f16 B-fragments fully in-register (named scalars, no stack object):
    // w_i = pkrtz(ps[2i], ps[2i+1]); permlane32_swap pairs (w0,w2),(w1,w3),(w4,w6),(w5,w7).
    // Resulting k-order within each 32-chunk is sigma (baked into Vt by transpose_v).
    f16x8 pb[2][2];
#pragma unroll
    for (int qg = 0; qg < 2; ++qg) {
      uint32_t w0, w1, w2, w3, w4, w5, w6, w7;
      asm("v_cvt_pkrtz_f16_f32 %0, %1, %2" : "=v"(w0) : "v"(ps[qg][0]),  "v"(ps[qg][1]));
      asm("v_cvt_pkrtz_f16_f32 %0, %1, %2" : "=v"(w1) : "v"(ps[qg][2]),  "v"(ps[qg][3]));
      asm("v_cvt_pkrtz_f16_f32 %0, %1, %2" : "=v"(w2) : "v"(ps[qg][4]),  "v"(ps[qg][5]));
      asm("v_cvt_pkrtz_f16_f32 %0, %1, %2" : "=v"(w3) : "v"(ps[qg][6]),  "v"(ps[qg][7]));
      asm("v_cvt_pkrtz_f16_f32 %0, %1, %2" : "=v"(w4) : "v"(ps[qg][8]),  "v"(ps[qg][9]));
      asm("v_cvt_pkrtz_f16_f32 %0, %1, %2" : "=v"(w5) : "v"(ps[qg][10]), "v"(ps[qg][11]));
      asm("v_cvt_pkrtz_f16_f32 %0, %1, %2" : "=v"(w6) : "v"(ps[qg][12]), "v"(ps[qg][13]));
      asm("v_cvt_pkrtz_f16_f32 %0, %1, %2" : "=v"(w7) : "v"(ps[qg][14]), "v"(ps[qg][15]));
      asm("v_permlane32_swap_b32 %0, %1" : "+v"(w0), "+v"(w2));
      asm("v_permlane32_swap_b32 %0, %1" : "+v"(w1), "+v"(w3));
      asm("v_permlane32_swap_b32 %0, %1" : "+v"(w4), "+v"(w6));
      asm("v_permlane32_swap_b32 %0, %1" : "+v"(w5), "+v"(w7));
      u32x4 c0 = { w0, w1, w2, w3 };
      u32x4 c1 = { w4, w5, w6, w7 };
      pb[qg][0] = __builtin_bit_cast(f16x8, c0);
      pb[qg][1] = __builtin_bit_cast(f16x8, c1);
    }

    // PV: each V fragment feeds both q-groups
    __builtin_amdgcn_s_setprio(1);
#pragma unroll
    for (int df = 0; df < 10; ++df)
#pragma unroll
      for (int ks = 0; ks < 2; ++ks) {
        f16x8 a = *(const f16x8*)(VlB + vro[ks] + df*2048);
        oacc[df][0] = __builtin_amdgcn_mfma_f32_16x16x32_f16(a, pb[0][ks], oacc[df][0], 0, 0, 0);
        oacc[df][1] = __builtin_amdgcn_mfma_f32_16x16x32_f16(a, pb[1][ks], oacc[df][1], 0, 0, 0);
      }
    __builtin_amdgcn_s_setprio(0);
    __syncthreads();
  }

#pragma unroll
  for (int qg = 0; qg < 2; ++qg) {
    float inv = 1.f / lsum[qg];
#pragma unroll
    for (int df = 0; df < 10; ++df)
#pragma unroll
      for (int pr = 0; pr < 2; ++pr) {
        f16x2 pv = { (f16)(oacc[df][qg][pr*2+0] * inv), (f16)(oacc[df][qg][pr*2+1] * inv) };
        *(f16x2*)&ctx[qrow[qg] * D_MODEL + h*HDIM + df*16 + lg*4 + pr*2] = pv;
      }
  }
}

// ---------------- launcher ----------------

extern "C" void kernel_launch(void* const* d_in, const int* in_sizes, int n_in,
                              void* d_out, int out_size, void* d_ws, size_t ws_size,
                              hipStream_t stream) {
  const float* x   = (const float*)d_in[0];
  const float* Wq  = (const float*)d_in[1];
  const float* Wk  = (const float*)d_in[2];
  const float* Wv  = (const float*)d_in[3];
  const float* Wo  = (const float*)d_in[4];
  const float* bo  = (const float*)d_in[5];
  const float* q_down = (const float*)d_in[6];
  const float* q_up   = (const float*)d_in[7];
  const float* k_down = (const float*)d_in[8];
  const float* k_up   = (const float*)d_in[9];
  const float* v_down = (const float*)d_in[10];
  const float* v_up   = (const float*)d_in[11];
  const float* o_down = (const float*)d_in[12];
  const float* o_up   = (const float*)d_in[13];
  float* out = (float*)d_out;

  char* ws = (char*)d_ws;
  f16* xh    = (f16*)ws;                                  // 8192x1280 (reused as ctx)
  f16* Wqkv  = (f16*)(ws + 20971520);                     // 3840x1280
  f16* WoE   = (f16*)(ws + 20971520 + 9830400);           // 1280x1280
  f16* qkv   = (f16*)(ws + 20971520 + 9830400 + 3276800); // 8192x3840
  f16* Vt    = (f16*)(ws + 20971520 + 9830400 + 3276800 + 62914560); // 32x160x2048
  f16* ctx   = xh;

  convert_f32_to_f16<<<(MTOT*D_MODEL/4 + 255)/256, 256, 0, stream>>>(x, xh, MTOT*D_MODEL/4);
  build_weff<<<D_MODEL*D_MODEL/4/256, 256, 0, stream>>>(Wq, q_up, q_down, Wqkv);
  build_weff<<<D_MODEL*D_MODEL/4/256, 256, 0, stream>>>(Wk, k_up, k_down, Wqkv + (size_t)D_MODEL*D_MODEL);
  build_weff<<<D_MODEL*D_MODEL/4/256, 256, 0, stream>>>(Wv, v_up, v_down, Wqkv + (size_t)2*D_MODEL*D_MODEL);
  build_weff<<<D_MODEL*D_MODEL/4/256, 256, 0, stream>>>(Wo, o_up, o_down, WoE);

  gemm256<<<dim3(NQKV/256, MTOT/256), 512, 0, stream>>>(xh, Wqkv, qkv);
  transpose_v<<<dim3(SEQ/32, HDIM/32, BATCH*HEADS), 256, 0, stream>>>(qkv, Vt);
  attn<<<dim3(SEQ/128, BATCH*HEADS), 256, 0, stream>>>(qkv, Vt, ctx);
  gemm_bt<0><<<dim3(D_MODEL/128, MTOT/128), 256, 0, stream>>>(ctx, D_MODEL, WoE, out, D_MODEL,
                                                              bo, D_MODEL, D_MODEL);
  (void)in_sizes; (void)n_in; (void)out_size; (void)ws_size;
}

// Round 9
// 290.008 us; speedup vs baseline: 1.5619x; 1.5619x over previous
//
#include <hip/hip_runtime.h>
#include <cstdint>

typedef _Float16 f16;
typedef f16 f16x8 __attribute__((ext_vector_type(8)));
typedef f16 f16x4 __attribute__((ext_vector_type(4)));
typedef f16 f16x2 __attribute__((ext_vector_type(2)));
typedef float f32x4 __attribute__((ext_vector_type(4)));
typedef uint32_t u32x4 __attribute__((ext_vector_type(4)));

#define D_MODEL 1280
#define SEQ 2048
#define BATCH 4
#define HEADS 8
#define HDIM 160
#define MTOT (BATCH*SEQ)          // 8192
#define NQKV (3*D_MODEL)          // 3840

__device__ __forceinline__ void gload_lds16(const f16* g, f16* l) {
  __builtin_amdgcn_global_load_lds(
      (const __attribute__((address_space(1))) unsigned int*)g,
      (__attribute__((address_space(3))) unsigned int*)l,
      16, 0, 0);
}

#define BARX() { asm volatile("" ::: "memory"); __builtin_amdgcn_s_barrier(); asm volatile("" ::: "memory"); }
#define VMW(N) { asm volatile("s_waitcnt vmcnt(" #N ")" ::: "memory"); }

// ---------------- prep kernels ----------------

__global__ void convert_f32_to_f16(const float* __restrict__ in, f16* __restrict__ out, int n4) {
  int i = blockIdx.x * 256 + threadIdx.x;
  if (i < n4) {
    float4 v = ((const float4*)in)[i];
    f16x4 o = { (f16)v.x, (f16)v.y, (f16)v.z, (f16)v.w };
    ((f16x4*)out)[i] = o;
  }
}

// W_eff[o][i] = W[o][i] + sum_r up[o][r]*down[r][i]   (all 1280x1280, rank 4)
__global__ void build_weff(const float* __restrict__ W, const float* __restrict__ up,
                           const float* __restrict__ down, f16* __restrict__ out) {
  int idx = blockIdx.x * 256 + threadIdx.x;          // D*D/4 threads
  int o  = idx / (D_MODEL / 4);
  int i0 = (idx % (D_MODEL / 4)) * 4;
  float4 w = *(const float4*)&W[(size_t)o * D_MODEL + i0];
  float u0 = up[o*4+0], u1 = up[o*4+1], u2 = up[o*4+2], u3 = up[o*4+3];
  float vals[4] = { w.x, w.y, w.z, w.w };
  f16x4 r;
#pragma unroll
  for (int j = 0; j < 4; ++j) {
    int i = i0 + j;
    float acc = vals[j] + u0*down[i] + u1*down[D_MODEL + i]
                        + u2*down[2*D_MODEL + i] + u3*down[3*D_MODEL + i];
    r[j] = (f16)acc;
  }
  *(f16x4*)&out[(size_t)o * D_MODEL + i0] = r;
}

// V slice of qkv [8192][3840] (cols 2560..3839) -> Vt [32 bh][160 d][2048 s]
// s-index sigma-permuted within each 32-block: sigma swaps 4-blocks [4-7]<->[8-11]
// and [20-23]<->[24-27] (involution), matching the in-register P layout.
__global__ void transpose_v(const f16* __restrict__ qkv, f16* __restrict__ Vt) {
  __shared__ f16 t[32][33];
  int s0 = blockIdx.x * 32;
  int d0 = blockIdx.y * 32;
  int bh = blockIdx.z;
  int b = bh >> 3, h = bh & 7;
  int j = threadIdx.x & 31;
  int i0 = threadIdx.x >> 5;
#pragma unroll
  for (int k = 0; k < 4; ++k) {
    int i = i0 + k * 8;
    t[i][j] = qkv[(size_t)(b*SEQ + s0 + i) * NQKV + 2*D_MODEL + h*HDIM + d0 + j];
  }
  __syncthreads();
  int sj = (((j>>2) ^ (j>>3)) & 1) ? (j ^ 12) : j;
#pragma unroll
  for (int k = 0; k < 4; ++k) {
    int i = i0 + k * 8;
    Vt[(size_t)(bh*HDIM + d0 + i) * SEQ + s0 + sj] = t[j][i];
  }
}

// ---------------- 256x256 deep-pipelined GEMM: C[M][N](f16) = A[M][K] * Bw[N][K]^T ----
__global__ __launch_bounds__(512) void gemm256(const f16* __restrict__ A,
                                               const f16* __restrict__ Bw,
                                               f16* __restrict__ C) {
  const int K = D_MODEL, ldc = NQKV, NT = D_MODEL/64;   // 20 K-tiles
  __shared__ alignas(16) f16 lds[7 * 8192];             // A: slots 0..2, B: slots 3..6
  f16* LB = lds + 3*8192;
  int tid = threadIdx.x;
  int wv = tid >> 6, l = tid & 63;
  int wm = wv >> 2, wn = wv & 3;
  int lr = l & 15, lg = l >> 4;
  int bm = blockIdx.y, bn = blockIdx.x;

  int row0 = tid >> 3;
  int csw  = ((tid & 7) ^ (row0 & 7)) * 8;
  const f16* Asrc[2]; const f16* Bsrc[2];
#pragma unroll
  for (int h = 0; h < 2; ++h) {
    Asrc[h] = A  + (size_t)(bm*256 + h*128 + row0) * K + csw;
    Bsrc[h] = Bw + (size_t)(bn*256 + h*128 + row0) * K + csw;
  }
  int ldsoff = wv * 512;

  int xsl0 = ((lg)     ^ (lr & 7)) * 8;
  int xsl1 = ((4 + lg) ^ (lr & 7)) * 8;

  f32x4 acc[8][4] = {};

#define STAGE_A(h, slot, kt) { const f16* s_ = Asrc[h] + (kt)*64; f16* d_ = lds + (slot)*8192 + ldsoff; \
    gload_lds16(s_, d_); gload_lds16(s_ + (size_t)64*K, d_ + 4096); }
#define STAGE_B(h, slot, kt) { const f16* s_ = Bsrc[h] + (kt)*64; f16* d_ = LB + (slot)*8192 + ldsoff; \
    gload_lds16(s_, d_); gload_lds16(s_ + (size_t)64*K, d_ + 4096); }

  STAGE_A(0, 0, 0); STAGE_A(1, 1, 0);
  STAGE_B(0, 0, 0); STAGE_B(1, 1, 0);
  STAGE_B(0, 2, 1);
  VMW(2); BARX();

  for (int t = 0; t < NT; ++t) {
    int sA0 = (2*t) % 3, sA1 = (2*t+1) % 3, sA2 = (2*t+2) % 3;
    int sB0 = (2*t) & 3, sB1 = (2*t+1) & 3, sB3 = (2*t+3) & 3;
    int tc1 = (t+1 < NT) ? t+1 : NT-1;
    int tc2 = (t+2 < NT) ? t+2 : NT-1;

#define PHASE(ah, bh, sA, sB, STG, VMOPT) { \
    f16x8 af[4][2], bf[2][2]; \
    _Pragma("unroll") \
    for (int j = 0; j < 4; ++j) { \
      int base = (sA)*8192 + (wm*64 + j*16 + lr)*64; \
      af[j][0] = *(const f16x8*)&lds[base + xsl0]; \
      af[j][1] = *(const f16x8*)&lds[base + xsl1]; \
    } \
    _Pragma("unroll") \
    for (int i = 0; i < 2; ++i) { \
      int base = (sB)*8192 + (wn*32 + i*16 + lr)*64; \
      bf[i][0] = *(const f16x8*)&LB[base + xsl0]; \
      bf[i][1] = *(const f16x8*)&LB[base + xsl1]; \
    } \
    STG; \
    BARX(); \
    __builtin_amdgcn_s_setprio(1); \
    _Pragma("unroll") \
    for (int j = 0; j < 4; ++j) \
      _Pragma("unroll") \
      for (int i = 0; i < 2; ++i) { \
        acc[(ah)*4+j][(bh)*2+i] = __builtin_amdgcn_mfma_f32_16x16x32_f16(af[j][0], bf[i][0], acc[(ah)*4+j][(bh)*2+i], 0, 0, 0); \
        acc[(ah)*4+j][(bh)*2+i] = __builtin_amdgcn_mfma_f32_16x16x32_f16(af[j][1], bf[i][1], acc[(ah)*4+j][(bh)*2+i], 0, 0, 0); \
      } \
    __builtin_amdgcn_s_setprio(0); \
    VMOPT; \
    BARX(); }

    PHASE(0, 0, sA0, sB0, STAGE_B(1, sB3, tc1), VMW(2))
    PHASE(1, 0, sA1, sB0, STAGE_A(0, sA2, tc1), )
    PHASE(0, 1, sA0, sB1, STAGE_B(0, sB0, tc2), )
    PHASE(1, 1, sA1, sB1, STAGE_A(1, sA0, tc1), VMW(4))
#undef PHASE
  }

#pragma unroll
  for (int mf = 0; mf < 8; ++mf) {
    int r0 = bm*256 + (mf>>2)*128 + wm*64 + (mf&3)*16 + lg*4;
#pragma unroll
    for (int nf = 0; nf < 4; ++nf) {
      int c = bn*256 + (nf>>1)*128 + wn*32 + (nf&1)*16 + lr;
#pragma unroll
      for (int rg = 0; rg < 4; ++rg)
        C[(size_t)(r0 + rg) * ldc + c] = (f16)acc[mf][nf][rg];
    }
  }
#undef STAGE_A
#undef STAGE_B
}

// ---------------- GEMM: C[M][N] = A[M][K] * Bw[N][K]^T  (+bias, f32 out) ----------------

template<int OUTF16>
__global__ __launch_bounds__(256) void gemm_bt(
    const f16* __restrict__ A, int lda,
    const f16* __restrict__ Bw,                 // [N][K], ldb = K
    void* __restrict__ Cp, int ldc,
    const float* __restrict__ bias,
    int N, int K) {
  __shared__ alignas(16) f16 As[128 * 32];
  __shared__ alignas(16) f16 Bs[128 * 32];
  int tid = threadIdx.x;
  int w = tid >> 6, l = tid & 63;
  int wm = w >> 1, wn = w & 1;
  int bm = blockIdx.y, bn = blockIdx.x;
  int lr = l & 15, lg = l >> 4;

  f32x4 acc[4][4] = {};

  const int srow = w * 32 + (l >> 2);
  const int scol = (l & 3) * 8;
  const f16* Ab = A  + (size_t)(bm*128 + srow) * lda + scol;
  const f16* Bb = Bw + (size_t)(bn*128 + srow) * K   + scol;
  f16* AsW = &As[w * 1024];
  f16* BsW = &Bs[w * 1024];

  for (int k0 = 0; k0 < K; k0 += 32) {
    gload_lds16(Ab + k0,                     AsW);
    gload_lds16(Ab + k0 + (size_t)16 * lda,  AsW + 512);
    gload_lds16(Bb + k0,                     BsW);
    gload_lds16(Bb + k0 + (size_t)16 * K,    BsW + 512);
    __syncthreads();
    f16x8 af[4], bf[4];
#pragma unroll
    for (int f = 0; f < 4; ++f) {
      af[f] = *(const f16x8*)&As[(wm*64 + f*16 + lr) * 32 + lg * 8];
      bf[f] = *(const f16x8*)&Bs[(wn*64 + f*16 + lr) * 32 + lg * 8];
    }
    __builtin_amdgcn_s_setprio(1);
#pragma unroll
    for (int fr = 0; fr < 4; ++fr)
#pragma unroll
      for (int fc = 0; fc < 4; ++fc)
        acc[fr][fc] = __builtin_amdgcn_mfma_f32_16x16x32_f16(af[fr], bf[fc], acc[fr][fc], 0, 0, 0);
    __builtin_amdgcn_s_setprio(0);
    __syncthreads();
  }

#pragma unroll
  for (int fr = 0; fr < 4; ++fr) {
    int r0 = bm*128 + wm*64 + fr*16 + lg*4;
#pragma unroll
    for (int fc = 0; fc < 4; ++fc) {
      int c = bn*128 + wn*64 + fc*16 + lr;
#pragma unroll
      for (int rg = 0; rg < 4; ++rg) {
        size_t off = (size_t)(r0 + rg) * ldc + c;
        if (OUTF16) ((f16*)Cp)[off] = (f16)acc[fr][fc][rg];
        else        ((float*)Cp)[off] = acc[fr][fc][rg] + bias[c];
      }
    }
  }
}

// ---------------- flash attention v4c ----------------
// v4b but with __launch_bounds__(256, 2): the (256,3) bound capped VGPRs at
// ~170 while peak live set is ~170+, causing a catastrophic scratch spill
// (~800 MB/dispatch HBM traffic, VGPR_Count 84). 256-cap compiles clean;
// hardware occupancy still reaches 3 blocks/CU if allocator lands <=168.
// Per-qg softmax finish (exp2 -> psum -> repack) shortens ps live ranges.
__global__ __launch_bounds__(256, 2) void attn(const f16* __restrict__ qkv,
                                               const f16* __restrict__ Vt,
                                               f16* __restrict__ ctx) {
  __shared__ alignas(16) f16 Kl[64 * 168];    // 21504 B
  __shared__ alignas(16) f16 Vl[160 * 64];    // 20480 B
  int tid = threadIdx.x;
  int wv = tid >> 6, l = tid & 63;
  int lr = l & 15, lg = l >> 4;
  int qt = blockIdx.x, bh = blockIdx.y;
  int b = bh >> 3, h = bh & 7;
  size_t qrow[2];
#pragma unroll
  for (int qg = 0; qg < 2; ++qg)
    qrow[qg] = (size_t)(b*SEQ + qt*128 + wv*32 + qg*16 + lr);

  // Q fragments, pre-scaled by hd^-0.5 * log2(e) (exp2 domain)
  const f16 qscale = (f16)0.114055069f;
  f16x8 qf[2][5];
#pragma unroll
  for (int qg = 0; qg < 2; ++qg)
#pragma unroll
    for (int dk = 0; dk < 5; ++dk) {
      f16x8 t = *(const f16x8*)&qkv[qrow[qg] * NQKV + h*HDIM + dk*32 + lg*8];
#pragma unroll
      for (int j = 0; j < 8; ++j) t[j] = t[j] * qscale;
      qf[qg][dk] = t;
    }

  // K staging: 1344 chunks (5x256 + 64 on wave 0); slot 20 = pad (garbage ok).
  const char* Kg0 = (const char*)qkv + (size_t)(b*SEQ)*NQKV*2 + (size_t)D_MODEL*2 + (size_t)h*HDIM*2;
  char* KlB = (char*)Kl;
  uint32_t koff[6];
  f16* kld[6];
#pragma unroll
  for (int it = 0; it < 6; ++it) {
    int p = (it < 5) ? it*256 + tid : 1280 + (tid & 63);
    koff[it] = (uint32_t)(p/21) * (NQKV*2) + (uint32_t)(p%21) * 16;
    kld[it] = (f16*)(KlB + ((it < 5) ? (it*256 + wv*64)*16 : 1280*16));
  }

  // V staging: 1280 chunks; content XOR-swizzled (phys slot sp holds logical sp^(row&7)).
  const char* Vg0 = (const char*)Vt + (size_t)bh*HDIM*SEQ*2;
  char* VlB = (char*)Vl;
  uint32_t voff[5];
  f16* vld[5];
#pragma unroll
  for (int it = 0; it < 5; ++it) {
    int c = it*256 + tid;
    int row = c >> 3, sp = c & 7;
    voff[it] = (uint32_t)row * (SEQ*2) + (uint32_t)((sp ^ (row & 7)) * 16);
    vld[it] = (f16*)(VlB + (it*256 + wv*64)*16);
  }
  uint32_t vro[2];
#pragma unroll
  for (int ks = 0; ks < 2; ++ks)
    vro[ks] = (uint32_t)lr*128 + (uint32_t)((((ks*4+lg) ^ (lr & 7)) * 16));

  f32x4 oacc[10][2] = {};
  float m[2] = {-1e30f, -1e30f}, lsum[2] = {0.f, 0.f};

  for (int kt = 0; kt < 32; ++kt) {
    const char* Ksrc = Kg0 + (size_t)kt * (64*NQKV*2);
    const char* Vsrc = Vg0 + (size_t)kt * 128;
#pragma unroll
    for (int it = 0; it < 5; ++it) {
      gload_lds16((const f16*)(Ksrc + koff[it]), kld[it]);
      gload_lds16((const f16*)(Vsrc + voff[it]), vld[it]);
    }
    if (wv == 0)
      gload_lds16((const f16*)(Ksrc + koff[5]), kld[5]);
    __syncthreads();

    // S^T[kr][q], both q-groups share each K fragment
    f32x4 sc[4][2] = {};
    __builtin_amdgcn_s_setprio(1);
#pragma unroll
    for (int kb = 0; kb < 4; ++kb)
#pragma unroll
      for (int dk = 0; dk < 5; ++dk) {
        f16x8 a = *(const f16x8*)&Kl[(kb*16 + lr)*168 + dk*32 + lg*8];
        sc[kb][0] = __builtin_amdgcn_mfma_f32_16x16x32_f16(a, qf[0][dk], sc[kb][0], 0, 0, 0);
        sc[kb][1] = __builtin_amdgcn_mfma_f32_16x16x32_f16(a, qf[1][dk], sc[kb][1], 0, 0, 0);
      }
    __builtin_amdgcn_s_setprio(0);

    // row maxes (both q-groups) for the defer-max decision
    float smax[2];
#pragma unroll
    for (int qg = 0; qg < 2; ++qg) {
      float sm = -1e30f;
#pragma unroll
      for (int kb = 0; kb < 4; ++kb)
#pragma unroll
        for (int rg = 0; rg < 4; ++rg) sm = fmaxf(sm, sc[kb][qg][rg]);
      sm = fmaxf(sm, __shfl_xor(sm, 16));
      sm = fmaxf(sm, __shfl_xor(sm, 32));
      smax[qg] = sm;
    }
    if (!__all(fmaxf(smax[0] - m[0], smax[1] - m[1]) <= 11.54f)) {
#pragma unroll
      for (int qg = 0; qg < 2; ++qg) {
        float mn = fmaxf(m[qg], smax[qg]);
        float alpha = exp2f(m[qg] - mn);
#pragma unroll
        for (int df = 0; df < 10; ++df)
#pragma unroll
          for (int rg = 0; rg < 4; ++rg) oacc[df][qg][rg] *= alpha;
        lsum[qg] *= alpha;
        m[qg] = mn;
      }
    }

    // per-qg: exp2 -> psum -> in-register repack (ps lives only inside this body)
    f16x8 pb[2][2];
#pragma unroll
    for (int qg = 0; qg < 2; ++qg) {
      float ps[16];
      float psum = 0.f;
#pragma unroll
      for (int kb = 0; kb < 4; ++kb)
#pragma unroll
        for (int rg = 0; rg < 4; ++rg) {
          float p = exp2f(sc[kb][qg][rg] - m[qg]);
          ps[kb*4 + rg] = p;
          psum += p;
        }
      psum += __shfl_xor(psum, 16);
      psum += __shfl_xor(psum, 32);
      lsum[qg] += psum;

      uint32_t w0, w1, w2, w3, w4, w5, w6, w7;
      asm("v_cvt_pkrtz_f16_f32 %0, %1, %2" : "=v"(w0) : "v"(ps[0]),  "v"(ps[1]));
      asm("v_cvt_pkrtz_f16_f32 %0, %1, %2" : "=v"(w1) : "v"(ps[2]),  "v"(ps[3]));
      asm("v_cvt_pkrtz_f16_f32 %0, %1, %2" : "=v"(w2) : "v"(ps[4]),  "v"(ps[5]));
      asm("v_cvt_pkrtz_f16_f32 %0, %1, %2" : "=v"(w3) : "v"(ps[6]),  "v"(ps[7]));
      asm("v_cvt_pkrtz_f16_f32 %0, %1, %2" : "=v"(w4) : "v"(ps[8]),  "v"(ps[9]));
      asm("v_cvt_pkrtz_f16_f32 %0, %1, %2" : "=v"(w5) : "v"(ps[10]), "v"(ps[11]));
      asm("v_cvt_pkrtz_f16_f32 %0, %1, %2" : "=v"(w6) : "v"(ps[12]), "v"(ps[13]));
      asm("v_cvt_pkrtz_f16_f32 %0, %1, %2" : "=v"(w7) : "v"(ps[14]), "v"(ps[15]));
      asm("v_permlane32_swap_b32 %0, %1" : "+v"(w0), "+v"(w2));
      asm("v_permlane32_swap_b32 %0, %1" : "+v"(w1), "+v"(w3));
      asm("v_permlane32_swap_b32 %0, %1" : "+v"(w4), "+v"(w6));
      asm("v_permlane32_swap_b32 %0, %1" : "+v"(w5), "+v"(w7));
      u32x4 c0 = { w0, w1, w2, w3 };
      u32x4 c1 = { w4, w5, w6, w7 };
      pb[qg][0] = __builtin_bit_cast(f16x8, c0);
      pb[qg][1] = __builtin_bit_cast(f16x8, c1);
    }

    // PV: each V fragment feeds both q-groups
    __builtin_amdgcn_s_setprio(1);
#pragma unroll
    for (int df = 0; df < 10; ++df)
#pragma unroll
      for (int ks = 0; ks < 2; ++ks) {
        f16x8 a = *(const f16x8*)(VlB + vro[ks] + df*2048);
        oacc[df][0] = __builtin_amdgcn_mfma_f32_16x16x32_f16(a, pb[0][ks], oacc[df][0], 0, 0, 0);
        oacc[df][1] = __builtin_amdgcn_mfma_f32_16x16x32_f16(a, pb[1][ks], oacc[df][1], 0, 0, 0);
      }
    __builtin_amdgcn_s_setprio(0);
    __syncthreads();
  }

#pragma unroll
  for (int qg = 0; qg < 2; ++qg) {
    float inv = 1.f / lsum[qg];
#pragma unroll
    for (int df = 0; df < 10; ++df)
#pragma unroll
      for (int pr = 0; pr < 2; ++pr) {
        f16x2 pv = { (f16)(oacc[df][qg][pr*2+0] * inv), (f16)(oacc[df][qg][pr*2+1] * inv) };
        *(f16x2*)&ctx[qrow[qg] * D_MODEL + h*HDIM + df*16 + lg*4 + pr*2] = pv;
      }
  }
}

// ---------------- launcher ----------------

extern "C" void kernel_launch(void* const* d_in, const int* in_sizes, int n_in,
                              void* d_out, int out_size, void* d_ws, size_t ws_size,
                              hipStream_t stream) {
  const float* x   = (const float*)d_in[0];
  const float* Wq  = (const float*)d_in[1];
  const float* Wk  = (const float*)d_in[2];
  const float* Wv  = (const float*)d_in[3];
  const float* Wo  = (const float*)d_in[4];
  const float* bo  = (const float*)d_in[5];
  const float* q_down = (const float*)d_in[6];
  const float* q_up   = (const float*)d_in[7];
  const float* k_down = (const float*)d_in[8];
  const float* k_up   = (const float*)d_in[9];
  const float* v_down = (const float*)d_in[10];
  const float* v_up   = (const float*)d_in[11];
  const float* o_down = (const float*)d_in[12];
  const float* o_up   = (const float*)d_in[13];
  float* out = (float*)d_out;

  char* ws = (char*)d_ws;
  f16* xh    = (f16*)ws;                                  // 8192x1280 (reused as ctx)
  f16* Wqkv  = (f16*)(ws + 20971520);                     // 3840x1280
  f16* WoE   = (f16*)(ws + 20971520 + 9830400);           // 1280x1280
  f16* qkv   = (f16*)(ws + 20971520 + 9830400 + 3276800); // 8192x3840
  f16* Vt    = (f16*)(ws + 20971520 + 9830400 + 3276800 + 62914560); // 32x160x2048
  f16* ctx   = xh;

  convert_f32_to_f16<<<(MTOT*D_MODEL/4 + 255)/256, 256, 0, stream>>>(x, xh, MTOT*D_MODEL/4);
  build_weff<<<D_MODEL*D_MODEL/4/256, 256, 0, stream>>>(Wq, q_up, q_down, Wqkv);
  build_weff<<<D_MODEL*D_MODEL/4/256, 256, 0, stream>>>(Wk, k_up, k_down, Wqkv + (size_t)D_MODEL*D_MODEL);
  build_weff<<<D_MODEL*D_MODEL/4/256, 256, 0, stream>>>(Wv, v_up, v_down, Wqkv + (size_t)2*D_MODEL*D_MODEL);
  build_weff<<<D_MODEL*D_MODEL/4/256, 256, 0, stream>>>(Wo, o_up, o_down, WoE);

  gemm256<<<dim3(NQKV/256, MTOT/256), 512, 0, stream>>>(xh, Wqkv, qkv);
  transpose_v<<<dim3(SEQ/32, HDIM/32, BATCH*HEADS), 256, 0, stream>>>(qkv, Vt);
  attn<<<dim3(SEQ/128, BATCH*HEADS), 256, 0, stream>>>(qkv, Vt, ctx);
  gemm_bt<0><<<dim3(D_MODEL/128, MTOT/128), 256, 0, stream>>>(ctx, D_MODEL, WoE, out, D_MODEL,
                                                              bo, D_MODEL, D_MODEL);
  (void)in_sizes; (void)n_in; (void)out_size; (void)ws_size;
}

// Round 10
// 282.457 us; speedup vs baseline: 1.6036x; 1.0267x over previous
//
#include <hip/hip_runtime.h>
#include <cstdint>

typedef _Float16 f16;
typedef f16 f16x8 __attribute__((ext_vector_type(8)));
typedef f16 f16x4 __attribute__((ext_vector_type(4)));
typedef f16 f16x2 __attribute__((ext_vector_type(2)));
typedef float f32x4 __attribute__((ext_vector_type(4)));
typedef uint32_t u32x4 __attribute__((ext_vector_type(4)));

#define D_MODEL 1280
#define SEQ 2048
#define BATCH 4
#define HEADS 8
#define HDIM 160
#define MTOT (BATCH*SEQ)          // 8192
#define NQKV (3*D_MODEL)          // 3840

__device__ __forceinline__ void gload_lds16(const f16* g, f16* l) {
  __builtin_amdgcn_global_load_lds(
      (const __attribute__((address_space(1))) unsigned int*)g,
      (__attribute__((address_space(3))) unsigned int*)l,
      16, 0, 0);
}

#define BARX() { asm volatile("" ::: "memory"); __builtin_amdgcn_s_barrier(); asm volatile("" ::: "memory"); }
#define VMW(N) { asm volatile("s_waitcnt vmcnt(" #N ")" ::: "memory"); }

// ---------------- prep kernels ----------------

__global__ void convert_f32_to_f16(const float* __restrict__ in, f16* __restrict__ out, int n4) {
  int i = blockIdx.x * 256 + threadIdx.x;
  if (i < n4) {
    float4 v = ((const float4*)in)[i];
    f16x4 o = { (f16)v.x, (f16)v.y, (f16)v.z, (f16)v.w };
    ((f16x4*)out)[i] = o;
  }
}

// W_eff[o][i] = W[o][i] + sum_r up[o][r]*down[r][i]   (all 1280x1280, rank 4)
__global__ void build_weff(const float* __restrict__ W, const float* __restrict__ up,
                           const float* __restrict__ down, f16* __restrict__ out) {
  int idx = blockIdx.x * 256 + threadIdx.x;          // D*D/4 threads
  int o  = idx / (D_MODEL / 4);
  int i0 = (idx % (D_MODEL / 4)) * 4;
  float4 w = *(const float4*)&W[(size_t)o * D_MODEL + i0];
  float u0 = up[o*4+0], u1 = up[o*4+1], u2 = up[o*4+2], u3 = up[o*4+3];
  float vals[4] = { w.x, w.y, w.z, w.w };
  f16x4 r;
#pragma unroll
  for (int j = 0; j < 4; ++j) {
    int i = i0 + j;
    float acc = vals[j] + u0*down[i] + u1*down[D_MODEL + i]
                        + u2*down[2*D_MODEL + i] + u3*down[3*D_MODEL + i];
    r[j] = (f16)acc;
  }
  *(f16x4*)&out[(size_t)o * D_MODEL + i0] = r;
}

// V slice of qkv -> Vt [32 bh][160 d][2048 s], s sigma-permuted within each
// 32-block (sigma swaps 4-blocks [4-7]<->[8-11], [20-23]<->[24-27]; involution)
// to match the in-register P layout. Vectorized f16x4 both sides.
__global__ void transpose_v(const f16* __restrict__ qkv, f16* __restrict__ Vt) {
  __shared__ f16 t[32][36];
  int s0 = blockIdx.x * 32;
  int d0 = blockIdx.y * 32;
  int bh = blockIdx.z;
  int b = bh >> 3, h = bh & 7;
  int tid = threadIdx.x;
  {
    int i = tid >> 3, j4 = (tid & 7) * 4;
    *(f16x4*)&t[i][j4] =
        *(const f16x4*)&qkv[(size_t)(b*SEQ + s0 + i) * NQKV + 2*D_MODEL + h*HDIM + d0 + j4];
  }
  __syncthreads();
  {
    int dd = tid >> 3, s4 = (tid & 7) * 4;
    f16x4 v;
#pragma unroll
    for (int k = 0; k < 4; ++k) {
      int s = s4 + k;
      int sj = (((s>>2) ^ (s>>3)) & 1) ? (s ^ 12) : s;
      v[k] = t[sj][dd];
    }
    *(f16x4*)&Vt[(size_t)(bh*HDIM + d0 + dd) * SEQ + s0 + s4] = v;
  }
}

// ---------------- 256x256 deep-pipelined GEMM ----------------
// C[M][N] = A[M][K] * Bw[N][K]^T; K=1280. OUTF32: float out + bias; else f16.
// XCD-aware bijective swizzle: xcd = flat&7 owns bm in [xcd*4, xcd*4+4).
template<int OUTF32>
__global__ __launch_bounds__(512) void gemm256(const f16* __restrict__ A,
                                               const f16* __restrict__ Bw,
                                               void* __restrict__ Cp, int ldc,
                                               const float* __restrict__ bias) {
  const int K = D_MODEL, NT = D_MODEL/64;               // 20 K-tiles
  __shared__ alignas(16) f16 lds[7 * 8192];             // A: slots 0..2, B: slots 3..6
  f16* LB = lds + 3*8192;
  int tid = threadIdx.x;
  int wv = tid >> 6, l = tid & 63;
  int wm = wv >> 2, wn = wv & 3;
  int lr = l & 15, lg = l >> 4;

  int flat = blockIdx.y * gridDim.x + blockIdx.x;
  int bnn = gridDim.x;
  int xcd = flat & 7, idx = flat >> 3;
  int bm = xcd * 4 + idx / bnn;
  int bn = idx % bnn;

  int row0 = tid >> 3;
  int csw  = ((tid & 7) ^ (row0 & 7)) * 8;
  const f16* Asrc[2]; const f16* Bsrc[2];
#pragma unroll
  for (int h = 0; h < 2; ++h) {
    Asrc[h] = A  + (size_t)(bm*256 + h*128 + row0) * K + csw;
    Bsrc[h] = Bw + (size_t)(bn*256 + h*128 + row0) * K + csw;
  }
  int ldsoff = wv * 512;

  int xsl0 = ((lg)     ^ (lr & 7)) * 8;
  int xsl1 = ((4 + lg) ^ (lr & 7)) * 8;

  f32x4 acc[8][4] = {};

#define STAGE_A(h, slot, kt) { const f16* s_ = Asrc[h] + (kt)*64; f16* d_ = lds + (slot)*8192 + ldsoff; \
    gload_lds16(s_, d_); gload_lds16(s_ + (size_t)64*K, d_ + 4096); }
#define STAGE_B(h, slot, kt) { const f16* s_ = Bsrc[h] + (kt)*64; f16* d_ = LB + (slot)*8192 + ldsoff; \
    gload_lds16(s_, d_); gload_lds16(s_ + (size_t)64*K, d_ + 4096); }

  STAGE_A(0, 0, 0); STAGE_A(1, 1, 0);
  STAGE_B(0, 0, 0); STAGE_B(1, 1, 0);
  STAGE_B(0, 2, 1);
  VMW(2); BARX();

  for (int t = 0; t < NT; ++t) {
    int sA0 = (2*t) % 3, sA1 = (2*t+1) % 3, sA2 = (2*t+2) % 3;
    int sB0 = (2*t) & 3, sB1 = (2*t+1) & 3, sB3 = (2*t+3) & 3;
    int tc1 = (t+1 < NT) ? t+1 : NT-1;
    int tc2 = (t+2 < NT) ? t+2 : NT-1;

#define PHASE(ah, bh, sA, sB, STG, VMOPT) { \
    f16x8 af[4][2], bf[2][2]; \
    _Pragma("unroll") \
    for (int j = 0; j < 4; ++j) { \
      int base = (sA)*8192 + (wm*64 + j*16 + lr)*64; \
      af[j][0] = *(const f16x8*)&lds[base + xsl0]; \
      af[j][1] = *(const f16x8*)&lds[base + xsl1]; \
    } \
    _Pragma("unroll") \
    for (int i = 0; i < 2; ++i) { \
      int base = (sB)*8192 + (wn*32 + i*16 + lr)*64; \
      bf[i][0] = *(const f16x8*)&LB[base + xsl0]; \
      bf[i][1] = *(const f16x8*)&LB[base + xsl1]; \
    } \
    STG; \
    BARX(); \
    __builtin_amdgcn_s_setprio(1); \
    _Pragma("unroll") \
    for (int j = 0; j < 4; ++j) \
      _Pragma("unroll") \
      for (int i = 0; i < 2; ++i) { \
        acc[(ah)*4+j][(bh)*2+i] = __builtin_amdgcn_mfma_f32_16x16x32_f16(af[j][0], bf[i][0], acc[(ah)*4+j][(bh)*2+i], 0, 0, 0); \
        acc[(ah)*4+j][(bh)*2+i] = __builtin_amdgcn_mfma_f32_16x16x32_f16(af[j][1], bf[i][1], acc[(ah)*4+j][(bh)*2+i], 0, 0, 0); \
      } \
    __builtin_amdgcn_s_setprio(0); \
    VMOPT; \
    BARX(); }

    PHASE(0, 0, sA0, sB0, STAGE_B(1, sB3, tc1), VMW(2))
    PHASE(1, 0, sA1, sB0, STAGE_A(0, sA2, tc1), )
    PHASE(0, 1, sA0, sB1, STAGE_B(0, sB0, tc2), )
    PHASE(1, 1, sA1, sB1, STAGE_A(1, sA0, tc1), VMW(4))
#undef PHASE
  }

#pragma unroll
  for (int mf = 0; mf < 8; ++mf) {
    int r0 = bm*256 + (mf>>2)*128 + wm*64 + (mf&3)*16 + lg*4;
#pragma unroll
    for (int nf = 0; nf < 4; ++nf) {
      int c = bn*256 + (nf>>1)*128 + wn*32 + (nf&1)*16 + lr;
      if constexpr (OUTF32) {
        float bb = bias[c];
#pragma unroll
        for (int rg = 0; rg < 4; ++rg)
          ((float*)Cp)[(size_t)(r0 + rg) * ldc + c] = acc[mf][nf][rg] + bb;
      } else {
#pragma unroll
        for (int rg = 0; rg < 4; ++rg)
          ((f16*)Cp)[(size_t)(r0 + rg) * ldc + c] = (f16)acc[mf][nf][rg];
      }
    }
  }
#undef STAGE_A
#undef STAGE_B
}

// ---------------- flash attention v5 ----------------
// v4c + XCD-aware block swizzle: XCD k owns bh in [4k, 4k+4) x 16 q-tiles,
// shrinking the per-XCD L2 K/V working set from 41 MB to 5.2 MB.
__global__ __launch_bounds__(256, 2) void attn(const f16* __restrict__ qkv,
                                               const f16* __restrict__ Vt,
                                               f16* __restrict__ ctx) {
  __shared__ alignas(16) f16 Kl[64 * 168];    // 21504 B
  __shared__ alignas(16) f16 Vl[160 * 64];    // 20480 B
  int tid = threadIdx.x;
  int wv = tid >> 6, l = tid & 63;
  int lr = l & 15, lg = l >> 4;
  int flat = blockIdx.y * 16 + blockIdx.x;    // 512 blocks
  int xcd = flat & 7, idx = flat >> 3;        // idx 0..63
  int bh = xcd * 4 + (idx >> 4);              // 4 bh per XCD
  int qt = idx & 15;
  int b = bh >> 3, h = bh & 7;
  size_t qrow[2];
#pragma unroll
  for (int qg = 0; qg < 2; ++qg)
    qrow[qg] = (size_t)(b*SEQ + qt*128 + wv*32 + qg*16 + lr);

  // Q fragments, pre-scaled by hd^-0.5 * log2(e) (exp2 domain)
  const f16 qscale = (f16)0.114055069f;
  f16x8 qf[2][5];
#pragma unroll
  for (int qg = 0; qg < 2; ++qg)
#pragma unroll
    for (int dk = 0; dk < 5; ++dk) {
      f16x8 t = *(const f16x8*)&qkv[qrow[qg] * NQKV + h*HDIM + dk*32 + lg*8];
#pragma unroll
      for (int j = 0; j < 8; ++j) t[j] = t[j] * qscale;
      qf[qg][dk] = t;
    }

  // K staging: 1344 chunks (5x256 + 64 on wave 0); slot 20 = pad (garbage ok).
  const char* Kg0 = (const char*)qkv + (size_t)(b*SEQ)*NQKV*2 + (size_t)D_MODEL*2 + (size_t)h*HDIM*2;
  char* KlB = (char*)Kl;
  uint32_t koff[6];
  f16* kld[6];
#pragma unroll
  for (int it = 0; it < 6; ++it) {
    int p = (it < 5) ? it*256 + tid : 1280 + (tid & 63);
    koff[it] = (uint32_t)(p/21) * (NQKV*2) + (uint32_t)(p%21) * 16;
    kld[it] = (f16*)(KlB + ((it < 5) ? (it*256 + wv*64)*16 : 1280*16));
  }

  // V staging: 1280 chunks; content XOR-swizzled (phys slot sp holds logical sp^(row&7)).
  const char* Vg0 = (const char*)Vt + (size_t)bh*HDIM*SEQ*2;
  char* VlB = (char*)Vl;
  uint32_t voff[5];
  f16* vld[5];
#pragma unroll
  for (int it = 0; it < 5; ++it) {
    int c = it*256 + tid;
    int row = c >> 3, sp = c & 7;
    voff[it] = (uint32_t)row * (SEQ*2) + (uint32_t)((sp ^ (row & 7)) * 16);
    vld[it] = (f16*)(VlB + (it*256 + wv*64)*16);
  }
  uint32_t vro[2];
#pragma unroll
  for (int ks = 0; ks < 2; ++ks)
    vro[ks] = (uint32_t)lr*128 + (uint32_t)((((ks*4+lg) ^ (lr & 7)) * 16));

  f32x4 oacc[10][2] = {};
  float m[2] = {-1e30f, -1e30f}, lsum[2] = {0.f, 0.f};

  for (int kt = 0; kt < 32; ++kt) {
    const char* Ksrc = Kg0 + (size_t)kt * (64*NQKV*2);
    const char* Vsrc = Vg0 + (size_t)kt * 128;
#pragma unroll
    for (int it = 0; it < 5; ++it) {
      gload_lds16((const f16*)(Ksrc + koff[it]), kld[it]);
      gload_lds16((const f16*)(Vsrc + voff[it]), vld[it]);
    }
    if (wv == 0)
      gload_lds16((const f16*)(Ksrc + koff[5]), kld[5]);
    __syncthreads();

    // S^T[kr][q], both q-groups share each K fragment
    f32x4 sc[4][2] = {};
    __builtin_amdgcn_s_setprio(1);
#pragma unroll
    for (int kb = 0; kb < 4; ++kb)
#pragma unroll
      for (int dk = 0; dk < 5; ++dk) {
        f16x8 a = *(const f16x8*)&Kl[(kb*16 + lr)*168 + dk*32 + lg*8];
        sc[kb][0] = __builtin_amdgcn_mfma_f32_16x16x32_f16(a, qf[0][dk], sc[kb][0], 0, 0, 0);
        sc[kb][1] = __builtin_amdgcn_mfma_f32_16x16x32_f16(a, qf[1][dk], sc[kb][1], 0, 0, 0);
      }
    __builtin_amdgcn_s_setprio(0);

    // row maxes (both q-groups) for the defer-max decision
    float smax[2];
#pragma unroll
    for (int qg = 0; qg < 2; ++qg) {
      float sm = -1e30f;
#pragma unroll
      for (int kb = 0; kb < 4; ++kb)
#pragma unroll
        for (int rg = 0; rg < 4; ++rg) sm = fmaxf(sm, sc[kb][qg][rg]);
      sm = fmaxf(sm, __shfl_xor(sm, 16));
      sm = fmaxf(sm, __shfl_xor(sm, 32));
      smax[qg] = sm;
    }
    if (!__all(fmaxf(smax[0] - m[0], smax[1] - m[1]) <= 11.54f)) {
#pragma unroll
      for (int qg = 0; qg < 2; ++qg) {
        float mn = fmaxf(m[qg], smax[qg]);
        float alpha = exp2f(m[qg] - mn);
#pragma unroll
        for (int df = 0; df < 10; ++df)
#pragma unroll
          for (int rg = 0; rg < 4; ++rg) oacc[df][qg][rg] *= alpha;
        lsum[qg] *= alpha;
        m[qg] = mn;
      }
    }

    // per-qg: exp2 -> psum -> in-register repack (ps lives only inside this body)
    f16x8 pb[2][2];
#pragma unroll
    for (int qg = 0; qg < 2; ++qg) {
      float ps[16];
      float psum = 0.f;
#pragma unroll
      for (int kb = 0; kb < 4; ++kb)
#pragma unroll
        for (int rg = 0; rg < 4; ++rg) {
          float p = exp2f(sc[kb][qg][rg] - m[qg]);
          ps[kb*4 + rg] = p;
          psum += p;
        }
      psum += __shfl_xor(psum, 16);
      psum += __shfl_xor(psum, 32);
      lsum[qg] += psum;

      uint32_t w0, w1, w2, w3, w4, w5, w6, w7;
      asm("v_cvt_pkrtz_f16_f32 %0, %1, %2" : "=v"(w0) : "v"(ps[0]),  "v"(ps[1]));
      asm("v_cvt_pkrtz_f16_f32 %0, %1, %2" : "=v"(w1) : "v"(ps[2]),  "v"(ps[3]));
      asm("v_cvt_pkrtz_f16_f32 %0, %1, %2" : "=v"(w2) : "v"(ps[4]),  "v"(ps[5]));
      asm("v_cvt_pkrtz_f16_f32 %0, %1, %2" : "=v"(w3) : "v"(ps[6]),  "v"(ps[7]));
      asm("v_cvt_pkrtz_f16_f32 %0, %1, %2" : "=v"(w4) : "v"(ps[8]),  "v"(ps[9]));
      asm("v_cvt_pkrtz_f16_f32 %0, %1, %2" : "=v"(w5) : "v"(ps[10]), "v"(ps[11]));
      asm("v_cvt_pkrtz_f16_f32 %0, %1, %2" : "=v"(w6) : "v"(ps[12]), "v"(ps[13]));
      asm("v_cvt_pkrtz_f16_f32 %0, %1, %2" : "=v"(w7) : "v"(ps[14]), "v"(ps[15]));
      asm("v_permlane32_swap_b32 %0, %1" : "+v"(w0), "+v"(w2));
      asm("v_permlane32_swap_b32 %0, %1" : "+v"(w1), "+v"(w3));
      asm("v_permlane32_swap_b32 %0, %1" : "+v"(w4), "+v"(w6));
      asm("v_permlane32_swap_b32 %0, %1" : "+v"(w5), "+v"(w7));
      u32x4 c0 = { w0, w1, w2, w3 };
      u32x4 c1 = { w4, w5, w6, w7 };
      pb[qg][0] = __builtin_bit_cast(f16x8, c0);
      pb[qg][1] = __builtin_bit_cast(f16x8, c1);
    }

    // PV: each V fragment feeds both q-groups
    __builtin_amdgcn_s_setprio(1);
#pragma unroll
    for (int df = 0; df < 10; ++df)
#pragma unroll
      for (int ks = 0; ks < 2; ++ks) {
        f16x8 a = *(const f16x8*)(VlB + vro[ks] + df*2048);
        oacc[df][0] = __builtin_amdgcn_mfma_f32_16x16x32_f16(a, pb[0][ks], oacc[df][0], 0, 0, 0);
        oacc[df][1] = __builtin_amdgcn_mfma_f32_16x16x32_f16(a, pb[1][ks], oacc[df][1], 0, 0, 0);
      }
    __builtin_amdgcn_s_setprio(0);
    __syncthreads();
  }

#pragma unroll
  for (int qg = 0; qg < 2; ++qg) {
    float inv = 1.f / lsum[qg];
#pragma unroll
    for (int df = 0; df < 10; ++df)
#pragma unroll
      for (int pr = 0; pr < 2; ++pr) {
        f16x2 pv = { (f16)(oacc[df][qg][pr*2+0] * inv), (f16)(oacc[df][qg][pr*2+1] * inv) };
        *(f16x2*)&ctx[qrow[qg] * D_MODEL + h*HDIM + df*16 + lg*4 + pr*2] = pv;
      }
  }
}

// ---------------- launcher ----------------

extern "C" void kernel_launch(void* const* d_in, const int* in_sizes, int n_in,
                              void* d_out, int out_size, void* d_ws, size_t ws_size,
                              hipStream_t stream) {
  const float* x   = (const float*)d_in[0];
  const float* Wq  = (const float*)d_in[1];
  const float* Wk  = (const float*)d_in[2];
  const float* Wv  = (const float*)d_in[3];
  const float* Wo  = (const float*)d_in[4];
  const float* bo  = (const float*)d_in[5];
  const float* q_down = (const float*)d_in[6];
  const float* q_up   = (const float*)d_in[7];
  const float* k_down = (const float*)d_in[8];
  const float* k_up   = (const float*)d_in[9];
  const float* v_down = (const float*)d_in[10];
  const float* v_up   = (const float*)d_in[11];
  const float* o_down = (const float*)d_in[12];
  const float* o_up   = (const float*)d_in[13];
  float* out = (float*)d_out;

  char* ws = (char*)d_ws;
  f16* xh    = (f16*)ws;                                  // 8192x1280 (reused as ctx)
  f16* Wqkv  = (f16*)(ws + 20971520);                     // 3840x1280
  f16* WoE   = (f16*)(ws + 20971520 + 9830400);           // 1280x1280
  f16* qkv   = (f16*)(ws + 20971520 + 9830400 + 3276800); // 8192x3840
  f16* Vt    = (f16*)(ws + 20971520 + 9830400 + 3276800 + 62914560); // 32x160x2048
  f16* ctx   = xh;

  convert_f32_to_f16<<<(MTOT*D_MODEL/4 + 255)/256, 256, 0, stream>>>(x, xh, MTOT*D_MODEL/4);
  build_weff<<<D_MODEL*D_MODEL/4/256, 256, 0, stream>>>(Wq, q_up, q_down, Wqkv);
  build_weff<<<D_MODEL*D_MODEL/4/256, 256, 0, stream>>>(Wk, k_up, k_down, Wqkv + (size_t)D_MODEL*D_MODEL);
  build_weff<<<D_MODEL*D_MODEL/4/256, 256, 0, stream>>>(Wv, v_up, v_down, Wqkv + (size_t)2*D_MODEL*D_MODEL);
  build_weff<<<D_MODEL*D_MODEL/4/256, 256, 0, stream>>>(Wo, o_up, o_down, WoE);

  gemm256<0><<<dim3(NQKV/256, MTOT/256), 512, 0, stream>>>(xh, Wqkv, qkv, NQKV, nullptr);
  transpose_v<<<dim3(SEQ/32, HDIM/32, BATCH*HEADS), 256, 0, stream>>>(qkv, Vt);
  attn<<<dim3(SEQ/128, BATCH*HEADS), 256, 0, stream>>>(qkv, Vt, ctx);
  gemm256<1><<<dim3(D_MODEL/256, MTOT/256), 512, 0, stream>>>(ctx, WoE, out, D_MODEL, bo);
  (void)in_sizes; (void)n_in; (void)out_size; (void)ws_size;
}